// Round 10
// baseline (302.135 us; speedup 1.0000x reference)
//
#include <hip/hip_runtime.h>
#include <hip/hip_bf16.h>
#include <hip/hip_cooperative_groups.h>
#include <stdint.h>

namespace cg = cooperative_groups;

typedef __bf16 bf16x8 __attribute__((ext_vector_type(8)));
typedef __bf16 bf16x4 __attribute__((ext_vector_type(4)));
typedef float  f32x4  __attribute__((ext_vector_type(4)));

#define RATIO 0.08838834764831845f
#define EPSV  1e-4f

#define GLOBAL_AS __attribute__((address_space(1)))
#define LDS_AS    __attribute__((address_space(3)))

static __device__ __forceinline__ void gload16(const void* g, void* l) {
  __builtin_amdgcn_global_load_lds((GLOBAL_AS const void*)g, (LDS_AS void*)l, 16, 0, 0);
}

// monotonic float<->uint key for exact atomicMax (all real keys > 0u)
static __device__ __forceinline__ unsigned fkey(float f) {
  unsigned b = __float_as_uint(f);
  return (b & 0x80000000u) ? ~b : (b | 0x80000000u);
}
static __device__ __forceinline__ float funkey(unsigned k) {
  unsigned b = (k & 0x80000000u) ? (k & 0x7FFFFFFFu) : ~k;
  return __uint_as_float(b);
}

// ---------------- workspace layout (bytes) ----------------
static constexpr size_t OFF_XB    = 0;                        // 16384*128*2
static constexpr size_t OFF_WCAT  = OFF_XB    + 4194304;
static constexpr size_t OFF_MQ    = OFF_WCAT  + 98304;
static constexpr size_t OFF_MK    = OFF_MQ    + 262144;
static constexpr size_t OFF_BCAT  = OFF_MK    + 262144;
static constexpr size_t OFF_BQF   = OFF_BCAT  + 2048;
static constexpr size_t OFF_BKF   = OFF_BQF   + 4096;
static constexpr size_t OFF_Y     = OFF_BKF   + 4096;         // 16384*384*4
static constexpr size_t OFF_QF    = OFF_Y     + 25165824;     // 8*2048*1024*2
static constexpr size_t OFF_KF    = OFF_QF    + 33554432;
static constexpr size_t OFF_KFT   = OFF_KF    + 33554432;
static constexpr size_t OFF_VFT   = OFF_KFT   + 33554432;     // 8*128*2048*2
static constexpr size_t OFF_KPART = OFF_VFT   + 4194304;      // 8*128*4 (fallback)
static constexpr size_t OFF_KMAX  = OFF_KPART + 4096;         // 64*4 atomic keys
static constexpr size_t OFF_KSPART= OFF_KMAX  + 1024;         // 16*8*1024*4
static constexpr size_t OFF_DPART = OFF_KSPART+ 524288;       // 8*8*2048*4
static constexpr size_t OFF_CTXP  = OFF_DPART + 524288;       // 4*8*128*1024*4
static constexpr size_t OFF_CTXT  = OFF_CTXP  + 16777216;     // 8*128*1024*2
static constexpr size_t WS_NEED   = OFF_CTXT  + 2097152;

// ---------------- shared NT-GEMM core: C(128x128) = A(tm:,*) * B(tn:,*)^T ----
static __device__ __forceinline__ void gemm_core(
    const __hip_bfloat16* __restrict__ A, const __hip_bfloat16* __restrict__ B,
    int lda, int ldb, int K, int tm, int tn,
    __bf16* As, __bf16* Bs, f32x4 acc[4][4]) {
  const int t    = threadIdx.x;
  const int w    = t >> 6;
  const int lane = t & 63;
  const int m_off = (w >> 1) << 6;
  const int n_off = (w & 1) << 6;
  const int r0 = t >> 2;
  const int kk = (t & 3) << 3;
  char* Asb = (char*)As + (w << 10);
  char* Bsb = (char*)Bs + (w << 10);
  const int frow = lane & 15;
  const int koff = (lane >> 4) << 3;
  for (int k0 = 0; k0 < K; k0 += 32) {
    const __hip_bfloat16* Ag = A + (size_t)(tm + r0) * lda + (k0 + kk);
    const __hip_bfloat16* Bg = B + (size_t)(tn + r0) * ldb + (k0 + kk);
    gload16(Ag, Asb);
    gload16(Ag + (size_t)64 * lda, Asb + 4096);
    gload16(Bg, Bsb);
    gload16(Bg + (size_t)64 * ldb, Bsb + 4096);
    __syncthreads();
    bf16x8 af[4], bfr[4];
#pragma unroll
    for (int mi = 0; mi < 4; ++mi)
      af[mi] = *(const bf16x8*)(As + ((m_off + mi * 16 + frow) << 5) + koff);
#pragma unroll
    for (int ni = 0; ni < 4; ++ni)
      bfr[ni] = *(const bf16x8*)(Bs + ((n_off + ni * 16 + frow) << 5) + koff);
#pragma unroll
    for (int mi = 0; mi < 4; ++mi)
#pragma unroll
      for (int ni = 0; ni < 4; ++ni)
        acc[mi][ni] = __builtin_amdgcn_mfma_f32_16x16x32_bf16(af[mi], bfr[ni], acc[mi][ni], 0, 0, 0);
    __syncthreads();
  }
}

#define ZERO_ACC(acc) do {                                   \
  _Pragma("unroll") for (int a_ = 0; a_ < 4; ++a_)           \
  _Pragma("unroll") for (int b_ = 0; b_ < 4; ++b_)           \
    acc[a_][b_] = (f32x4){0.f, 0.f, 0.f, 0.f};               \
} while (0)

// ---------------- fused prep kernel ----------------
__global__ void k_prep(const float* __restrict__ x,
                       const float* __restrict__ Wq, const float* __restrict__ bq,
                       const float* __restrict__ Wk, const float* __restrict__ bk,
                       const float* __restrict__ Wv, const float* __restrict__ bv,
                       const float* __restrict__ proj,
                       __hip_bfloat16* __restrict__ xb,
                       __hip_bfloat16* __restrict__ Wcat, float* __restrict__ bcat,
                       __hip_bfloat16* __restrict__ Mq, __hip_bfloat16* __restrict__ Mk,
                       float* __restrict__ bqf, float* __restrict__ bkf,
                       unsigned* __restrict__ kmaxI) {
  const int b = blockIdx.x, t = threadIdx.x;
  { // convx: all 2048 blocks
    int i = (b * 256 + t) * 4;
    f32x4 v = *(const f32x4*)(x + i);
#pragma unroll
    for (int j = 0; j < 4; ++j) xb[i + j] = __float2bfloat16(v[j]);
  }
  if (b == 0 && t < 64) kmaxI[t] = 0u;
  if (b < 1024) { // prepM
    int i = b * 256 + t;
    {
      int which = i >> 17;
      int rem = i & 131071;
      int hj = rem >> 7, e = rem & 127;
      int hh = hj >> 7, j = hj & 127;
      const float* W = which ? Wk : Wq;
      float s = 0.f;
#pragma unroll
      for (int u = 0; u < 16; ++u) s += proj[j * 16 + u] * W[(hh * 16 + u) * 128 + e];
      if (which) Mk[rem] = __float2bfloat16(0.5f * s);
      else       Mq[rem] = __float2bfloat16(0.5f * s);
    }
    if (i < 2048) {
      int which = i >> 10;
      int hj = i & 1023, hh = hj >> 7, j = hj & 127;
      const float* bb = which ? bk : bq;
      float s = 0.f;
#pragma unroll
      for (int u = 0; u < 16; ++u) s += proj[j * 16 + u] * bb[hh * 16 + u];
      if (which) bkf[hj] = 0.5f * s;
      else       bqf[hj] = 0.5f * s;
    }
  }
  if (b < 192) { // prepwb
    int i = b * 256 + t;
    int mat = i >> 14, rem = i & 16383;
    const float* W = (mat == 0) ? Wq : ((mat == 1) ? Wk : Wv);
    Wcat[i] = __float2bfloat16(W[rem]);
    if (i < 384) {
      int m2 = i >> 7;
      const float* bb = (m2 == 0) ? bq : ((m2 == 1) ? bk : bv);
      bcat[i] = bb[i & 127];
    }
  }
}

// ---------------- projection GEMM: Y = x*Wcat^T + bcat; V-part -> vfT --------
__global__ __launch_bounds__(256) void k_proj(
    const __hip_bfloat16* __restrict__ xb, const __hip_bfloat16* __restrict__ Wcat,
    const float* __restrict__ bcat, float* __restrict__ Y,
    __hip_bfloat16* __restrict__ vfT) {
  __shared__ __align__(16) char pool[34816];
  __bf16* As = (__bf16*)pool;
  __bf16* Bs = (__bf16*)(pool + 8192);
  const int tm = blockIdx.x << 7, tn = blockIdx.y << 7;
  f32x4 acc[4][4];
  ZERO_ACC(acc);
  gemm_core(xb, Wcat, 128, 128, 128, tm, tn, As, Bs, acc);
  const int t = threadIdx.x, w = t >> 6, lane = t & 63;
  const int m_off = (w >> 1) << 6, n_off = (w & 1) << 6;
  const int frow = lane & 15;
  if (tn == 256) {
    __bf16* vT = (__bf16*)pool;
#pragma unroll
    for (int ni = 0; ni < 4; ++ni) {
      const int j = n_off + ni * 16 + frow;
      const float bias = bcat[256 + j];
#pragma unroll
      for (int mi = 0; mi < 4; ++mi)
#pragma unroll
        for (int i = 0; i < 4; ++i) {
          const int rl = m_off + mi * 16 + ((lane >> 4) << 2) + i;
          vT[j * 136 + rl] = (__bf16)(acc[mi][ni][i] + bias);
        }
    }
    __syncthreads();
    const int r = tm >> 11, c0 = tm & 2047;
    const int j2 = t >> 1, half = t & 1;
    const int hh = j2 >> 4, aa = j2 & 15;
    __bf16* dst = (__bf16*)vfT + (((size_t)(hh * 128 + r * 16 + aa)) << 11) + c0 + (half << 6);
    const __bf16* srcr = vT + j2 * 136 + (half << 6);
#pragma unroll
    for (int q8 = 0; q8 < 8; ++q8)
      *(bf16x8*)(dst + (q8 << 3)) = *(const bf16x8*)(srcr + (q8 << 3));
  } else {
#pragma unroll
    for (int ni = 0; ni < 4; ++ni) {
      const int col = tn + n_off + ni * 16 + frow;
      const float bias = bcat[col];
#pragma unroll
      for (int mi = 0; mi < 4; ++mi)
#pragma unroll
        for (int i = 0; i < 4; ++i) {
          const int row = tm + m_off + mi * 16 + ((lane >> 4) << 2) + i;
          Y[(size_t)row * 384 + col] = acc[mi][ni][i] + bias;
        }
    }
  }
}

// ---------------- k dash+features, single cooperative pass ----------------
__global__ __launch_bounds__(256, 4) void k_dashk_coop(
    const __hip_bfloat16* __restrict__ xb, const __hip_bfloat16* __restrict__ Mk,
    const float* __restrict__ bkf, const float* __restrict__ Y,
    unsigned* __restrict__ kmaxI,
    __hip_bfloat16* __restrict__ kf, __hip_bfloat16* __restrict__ kfT,
    float* __restrict__ kspart) {
  __shared__ __align__(16) char pool[34816];   // As/Bs during GEMM; kT after
  __shared__ float diag_s[128];
  __shared__ float wmax_s[4];
  __shared__ float m_s;
  __shared__ float ksp_s[2][128];
  __bf16* As = (__bf16*)pool;
  __bf16* Bs = (__bf16*)(pool + 8192);
  __bf16* kT = (__bf16*)pool;
  const int h = blockIdx.y;
  const int tm = blockIdx.x << 7;
  const int t = threadIdx.x, w = t >> 6, lane = t & 63;
  if (t < 128) {
    const float* yp = Y + (size_t)(tm + t) * 384 + 128 + h * 16;
    float s = 0.f;
#pragma unroll
    for (int u = 0; u < 16; ++u) s += yp[u] * yp[u];
    diag_s[t] = 0.125f * s;
  }
  f32x4 acc[4][4];
  ZERO_ACC(acc);
  gemm_core(xb, Mk + h * 16384, 128, 128, 128, tm, 0, As, Bs, acc);
  const int m_off = (w >> 1) << 6, n_off = (w & 1) << 6;
  const int frow = lane & 15;
  const int r = tm >> 11;
  const int c0 = tm & 2047;
  const int cb = blockIdx.x & 15;
  float bia[4];
#pragma unroll
  for (int ni = 0; ni < 4; ++ni) bia[ni] = bkf[h * 128 + n_off + ni * 16 + frow];
  // block max
  float mx = -1e30f;
#pragma unroll
  for (int ni = 0; ni < 4; ++ni)
#pragma unroll
    for (int mi = 0; mi < 4; ++mi)
#pragma unroll
      for (int i = 0; i < 4; ++i) mx = fmaxf(mx, acc[mi][ni][i] + bia[ni]);
#pragma unroll
  for (int off = 1; off < 64; off <<= 1) mx = fmaxf(mx, __shfl_xor(mx, off));
  if (lane == 0) wmax_s[w] = mx;
  __syncthreads();
  if (t == 0) {
    float bm = fmaxf(fmaxf(wmax_s[0], wmax_s[1]), fmaxf(wmax_s[2], wmax_s[3]));
    atomicMax(&kmaxI[r * 8 + h], fkey(bm));
  }
  cg::this_grid().sync();
  if (t == 0) m_s = funkey(atomicMax(&kmaxI[r * 8 + h], 0u));
  __syncthreads();
  const float m = m_s;
  float ksp[4] = {0.f, 0.f, 0.f, 0.f};
#pragma unroll
  for (int mi = 0; mi < 4; ++mi) {
#pragma unroll
    for (int i = 0; i < 4; ++i) {
      const int rl = m_off + mi * 16 + ((lane >> 4) << 2) + i;
      const int c = c0 + rl;
      const float dm = diag_s[rl] + m;
#pragma unroll
      for (int ni = 0; ni < 4; ++ni) {
        const int j = n_off + ni * 16 + frow;
        const float f = RATIO * (__expf(acc[mi][ni][i] + bia[ni] - dm) + EPSV);
        const __hip_bfloat16 hb = __float2bfloat16(f);
        kf[((size_t)((h << 11) + c) << 10) + (r << 7) + j] = hb;
        kT[j * 136 + rl] = (__bf16)f;
        ksp[ni] += __bfloat162float(hb);
      }
    }
  }
#pragma unroll
  for (int ni = 0; ni < 4; ++ni) {
    ksp[ni] += __shfl_xor(ksp[ni], 16);
    ksp[ni] += __shfl_xor(ksp[ni], 32);
  }
  if ((lane >> 4) == 0) {
#pragma unroll
    for (int ni = 0; ni < 4; ++ni)
      ksp_s[w >> 1][n_off + ni * 16 + frow] = ksp[ni];
  }
  __syncthreads();
  if (t < 128)
    kspart[(((cb << 3) + h) << 10) + r * 128 + t] = ksp_s[0][t] + ksp_s[1][t];
  const int j2 = t >> 1, half = t & 1;
  __bf16* dst = (__bf16*)kfT + (((size_t)(h << 10) + (r << 7) + j2) << 11) + c0 + (half << 6);
  const __bf16* srcr = kT + j2 * 136 + (half << 6);
#pragma unroll
  for (int q8 = 0; q8 < 8; ++q8)
    *(bf16x8*)(dst + (q8 << 3)) = *(const bf16x8*)(srcr + (q8 << 3));
}

// ---------------- fallback: k features pass A (max) ----------------
__global__ __launch_bounds__(256) void k_dashk_max(
    const __hip_bfloat16* __restrict__ xb, const __hip_bfloat16* __restrict__ Mk,
    const float* __restrict__ bkf, float* __restrict__ kpart) {
  __shared__ __align__(16) __bf16 As[4096], Bs[4096];
  __shared__ float wmax[4];
  const int h = blockIdx.y;
  const int tm = blockIdx.x << 7;
  f32x4 acc[4][4];
  ZERO_ACC(acc);
  gemm_core(xb, Mk + h * 16384, 128, 128, 128, tm, 0, As, Bs, acc);
  const int t = threadIdx.x, w = t >> 6, lane = t & 63;
  const int n_off = (w & 1) << 6;
  float mx = -1e30f;
#pragma unroll
  for (int ni = 0; ni < 4; ++ni) {
    const float bia = bkf[h * 128 + n_off + ni * 16 + (lane & 15)];
#pragma unroll
    for (int mi = 0; mi < 4; ++mi)
#pragma unroll
      for (int i = 0; i < 4; ++i) mx = fmaxf(mx, acc[mi][ni][i] + bia);
  }
#pragma unroll
  for (int off = 1; off < 64; off <<= 1) mx = fmaxf(mx, __shfl_xor(mx, off));
  if (lane == 0) wmax[w] = mx;
  __syncthreads();
  if (t == 0) kpart[h * 128 + blockIdx.x] = fmaxf(fmaxf(wmax[0], wmax[1]), fmaxf(wmax[2], wmax[3]));
}

// ---------------- fallback: k features pass B ----------------
__global__ __launch_bounds__(256) void k_dashk_feat(
    const __hip_bfloat16* __restrict__ xb, const __hip_bfloat16* __restrict__ Mk,
    const float* __restrict__ bkf, const float* __restrict__ Y,
    const float* __restrict__ kpart,
    __hip_bfloat16* __restrict__ kf, __hip_bfloat16* __restrict__ kfT,
    float* __restrict__ kspart) {
  __shared__ __align__(16) __bf16 As[4096], Bs[4096];
  __shared__ float diag_s[128];
  __shared__ __align__(16) __bf16 kT[128 * 136];
  __shared__ float ksp_s[2][128];
  const int h = blockIdx.y;
  const int tm = blockIdx.x << 7;
  f32x4 acc[4][4];
  ZERO_ACC(acc);
  gemm_core(xb, Mk + h * 16384, 128, 128, 128, tm, 0, As, Bs, acc);
  const int t = threadIdx.x, w = t >> 6, lane = t & 63;
  const int m_off = (w >> 1) << 6, n_off = (w & 1) << 6;
  const int frow = lane & 15;
  if (t < 128) {
    const float* yp = Y + (size_t)(tm + t) * 384 + 128 + h * 16;
    float s = 0.f;
#pragma unroll
    for (int u = 0; u < 16; ++u) s += yp[u] * yp[u];
    diag_s[t] = 0.125f * s;
  }
  const int r = tm >> 11;
  const int c0 = tm & 2047;
  const int cb = blockIdx.x & 15;
  float m = -1e30f;
  {
    const float* kp = kpart + h * 128 + r * 16;
#pragma unroll
    for (int i = 0; i < 16; ++i) m = fmaxf(m, kp[i]);
  }
  float bia[4];
#pragma unroll
  for (int ni = 0; ni < 4; ++ni) bia[ni] = bkf[h * 128 + n_off + ni * 16 + frow];
  float ksp[4] = {0.f, 0.f, 0.f, 0.f};
  __syncthreads();
#pragma unroll
  for (int mi = 0; mi < 4; ++mi) {
#pragma unroll
    for (int i = 0; i < 4; ++i) {
      const int rl = m_off + mi * 16 + ((lane >> 4) << 2) + i;
      const int c = c0 + rl;
      const float dm = diag_s[rl] + m;
#pragma unroll
      for (int ni = 0; ni < 4; ++ni) {
        const int j = n_off + ni * 16 + frow;
        const float f = RATIO * (__expf(acc[mi][ni][i] + bia[ni] - dm) + EPSV);
        const __hip_bfloat16 hb = __float2bfloat16(f);
        kf[((size_t)((h << 11) + c) << 10) + (r << 7) + j] = hb;
        kT[j * 136 + rl] = (__bf16)f;
        ksp[ni] += __bfloat162float(hb);
      }
    }
  }
#pragma unroll
  for (int ni = 0; ni < 4; ++ni) {
    ksp[ni] += __shfl_xor(ksp[ni], 16);
    ksp[ni] += __shfl_xor(ksp[ni], 32);
  }
  if ((lane >> 4) == 0) {
#pragma unroll
    for (int ni = 0; ni < 4; ++ni)
      ksp_s[w >> 1][n_off + ni * 16 + frow] = ksp[ni];
  }
  __syncthreads();
  if (t < 128)
    kspart[(((cb << 3) + h) << 10) + r * 128 + t] = ksp_s[0][t] + ksp_s[1][t];
  const int j2 = t >> 1, half = t & 1;
  __bf16* dst = (__bf16*)kfT + (((size_t)(h << 10) + (r << 7) + j2) << 11) + c0 + (half << 6);
  const __bf16* srcr = kT + j2 * 136 + (half << 6);
#pragma unroll
  for (int q8 = 0; q8 < 8; ++q8)
    *(bf16x8*)(dst + (q8 << 3)) = *(const bf16x8*)(srcr + (q8 << 3));
}

// ---------------- q features (r4 epilogue + fused D_inv partial dot) ---------
__global__ __launch_bounds__(256) void k_dashq(
    const __hip_bfloat16* __restrict__ xb, const __hip_bfloat16* __restrict__ Mq,
    const float* __restrict__ bqf, const float* __restrict__ Y,
    const float* __restrict__ kspart,
    __hip_bfloat16* __restrict__ qf, float* __restrict__ dpart) {
  __shared__ __align__(16) __bf16 As[4096], Bs[4096];
  __shared__ float diag_s[128];
  __shared__ float rmax_s[2][128];
  __shared__ float ksum_s[128];
  __shared__ float dred_s[2][128];
  const int h = blockIdx.y;
  const int tm = blockIdx.x << 7;
  const int r = tm >> 11, c0 = tm & 2047;
  f32x4 acc[4][4];
  ZERO_ACC(acc);
  const int t = threadIdx.x, w = t >> 6, lane = t & 63;
  if (t < 128) {
    const float* yp = Y + (size_t)(tm + t) * 384 + h * 16;
    float s = 0.f;
#pragma unroll
    for (int u = 0; u < 16; ++u) s += yp[u] * yp[u];
    diag_s[t] = 0.125f * s;
    float ks = 0.f;
#pragma unroll
    for (int cb = 0; cb < 16; ++cb) ks += kspart[(((cb << 3) + h) << 10) + r * 128 + t];
    ksum_s[t] = ks;
  }
  gemm_core(xb, Mq + h * 16384, 128, 128, 128, tm, 0, As, Bs, acc);
  const int m_off = (w >> 1) << 6, n_off = (w & 1) << 6;
  const int frow = lane & 15;
  float bia[4];
#pragma unroll
  for (int ni = 0; ni < 4; ++ni) bia[ni] = bqf[h * 128 + n_off + ni * 16 + frow];
  float rmx[4][4];
#pragma unroll
  for (int mi = 0; mi < 4; ++mi)
#pragma unroll
    for (int i = 0; i < 4; ++i) {
      float m0 = acc[mi][0][i] + bia[0];
      m0 = fmaxf(m0, acc[mi][1][i] + bia[1]);
      m0 = fmaxf(m0, acc[mi][2][i] + bia[2]);
      m0 = fmaxf(m0, acc[mi][3][i] + bia[3]);
      rmx[mi][i] = m0;
    }
#pragma unroll
  for (int off = 1; off < 16; off <<= 1)
#pragma unroll
    for (int mi = 0; mi < 4; ++mi)
#pragma unroll
      for (int i = 0; i < 4; ++i)
        rmx[mi][i] = fmaxf(rmx[mi][i], __shfl_xor(rmx[mi][i], off));
  if (frow == 0) {
#pragma unroll
    for (int mi = 0; mi < 4; ++mi)
#pragma unroll
      for (int i = 0; i < 4; ++i)
        rmax_s[w & 1][m_off + mi * 16 + ((lane >> 4) << 2) + i] = rmx[mi][i];
  }
  __syncthreads();
  float p[4][4];
#pragma unroll
  for (int mi = 0; mi < 4; ++mi)
#pragma unroll
    for (int i = 0; i < 4; ++i) p[mi][i] = 0.f;
#pragma unroll
  for (int mi = 0; mi < 4; ++mi) {
#pragma unroll
    for (int i = 0; i < 4; ++i) {
      const int rl = m_off + mi * 16 + ((lane >> 4) << 2) + i;
      const float md = diag_s[rl] + fmaxf(rmax_s[0][rl], rmax_s[1][rl]);
#pragma unroll
      for (int ni = 0; ni < 4; ++ni) {
        const int j = n_off + ni * 16 + frow;
        const float f = RATIO * (__expf(acc[mi][ni][i] + bia[ni] - md) + EPSV);
        const __hip_bfloat16 hb = __float2bfloat16(f);
        qf[((size_t)((h << 11) + c0 + rl) << 10) + (r << 7) + j] = hb;
        p[mi][i] += __bfloat162float(hb) * ksum_s[j];
      }
    }
  }
#pragma unroll
  for (int off = 1; off < 16; off <<= 1)
#pragma unroll
    for (int mi = 0; mi < 4; ++mi)
#pragma unroll
      for (int i = 0; i < 4; ++i)
        p[mi][i] += __shfl_xor(p[mi][i], off);
  if (frow == 0) {
#pragma unroll
    for (int mi = 0; mi < 4; ++mi)
#pragma unroll
      for (int i = 0; i < 4; ++i)
        dred_s[w & 1][m_off + mi * 16 + ((lane >> 4) << 2) + i] = p[mi][i];
  }
  __syncthreads();
  if (t < 128)
    dpart[(((r << 3) + h) << 11) + c0 + t] = dred_s[0][t] + dred_s[1][t];
}

// ---------------- attn GEMM: 256x256, BK=64, 4-phase (lockstep barriers cut) -
#define SBAR() __builtin_amdgcn_s_barrier()
#define FEN()  do { asm volatile("" ::: "memory"); __builtin_amdgcn_sched_barrier(0); } while (0)
#define PRIO1() __builtin_amdgcn_s_setprio(1)
#define PRIO0() __builtin_amdgcn_s_setprio(0)
#define VMW4() do { asm volatile("s_waitcnt vmcnt(4)" ::: "memory"); } while (0)
#define VMW0() do { asm volatile("s_waitcnt vmcnt(0)" ::: "memory"); } while (0)

#define MFMA16(nlo) do {                                                      \
  _Pragma("unroll") for (int mi_ = 0; mi_ < 8; ++mi_)                         \
  _Pragma("unroll") for (int nj_ = 0; nj_ < 2; ++nj_)                         \
    acc[mi_][(nlo) + nj_] = __builtin_amdgcn_mfma_f32_16x16x32_bf16(          \
        aR[mi_], bR[nj_], acc[mi_][(nlo) + nj_], 0, 0, 0);                    \
} while (0)

__global__ __launch_bounds__(512, 2) void k_attn8(
    const __hip_bfloat16* __restrict__ qf, const __hip_bfloat16* __restrict__ kf,
    float* __restrict__ attn) {
  extern __shared__ __align__(128) char lds[];
  const int lid = blockIdx.x;
  const int swz = ((lid & 7) << 6) + (lid >> 3);
  const int h  = swz >> 6;
  const int tm = ((swz >> 3) & 7) << 8;
  const int tn = (swz & 7) << 8;
  const __hip_bfloat16* Ag = qf + ((size_t)h << 21);
  const __hip_bfloat16* Bg = kf + ((size_t)h << 21);

  const int t = threadIdx.x, wid = t >> 6, lane = t & 63;
  const int f = lane & 15;
  const int wr = wid >> 2, wc = wid & 3;
  const int swzg = (((lane >> 4) ^ ((f >> 1) & 3)) << 4);
  const int aoff = ((wr << 7) + f) * 64 + swzg;
  const int boff = 65536 + ((wc << 6) + f) * 64 + swzg;
  const int srow = t >> 2;
  const int scol = (((t & 3) ^ ((t >> 3) & 3)) << 3);
  const int sdst = wid << 10;

  f32x4 acc[8][4] = {};
  bf16x8 aR[8], bR[2];

  auto stageA = [&](int buf, int kh, int k0) {
    char* d = lds + buf * 32768 + kh * 16384 + sdst;
    const __hip_bfloat16* g = Ag + (size_t)(tm + srow) * 1024 + k0 + (kh << 5) + scol;
    gload16(g, d);
    gload16(g + 128 * 1024, d + 8192);
  };
  auto stageB = [&](int buf, int kh, int k0) {
    char* d = lds + 65536 + buf * 32768 + kh * 16384 + sdst;
    const __hip_bfloat16* g = Bg + (size_t)(tn + srow) * 1024 + k0 + (kh << 5) + scol;
    gload16(g, d);
    gload16(g + 128 * 1024, d + 8192);
  };

  stageA(0, 0, 0); stageB(0, 0, 0); stageA(0, 1, 0); stageB(0, 1, 0);
  VMW4();
  SBAR(); FEN();

  for (int kt = 0; kt < 15; ++kt) {
    const int buf = kt & 1, nbuf = buf ^ 1;
    const int bo = buf * 32768;
    const int nk0 = (kt + 1) << 6;
#pragma unroll
    for (int mi = 0; mi < 8; ++mi) aR[mi] = *(const bf16x8*)(lds + bo + aoff + mi * 1024);
    bR[0] = *(const bf16x8*)(lds + bo + boff);
    bR[1] = *(const bf16x8*)(lds + bo + boff + 1024);
    stageA(nbuf, 0, nk0);
    PRIO1(); MFMA16(0); PRIO0();
    bR[0] = *(const bf16x8*)(lds + bo + boff + 2048);
    bR[1] = *(const bf16x8*)(lds + bo + boff + 3072);
    stageB(nbuf, 0, nk0);
    PRIO1(); MFMA16(2); PRIO0();
    VMW4();
    SBAR(); FEN();
#pragma unroll
    for (int mi = 0; mi < 8; ++mi) aR[mi] = *(const bf16x8*)(lds + bo + 16384 + aoff + mi * 1024);
    bR[0] = *(const bf16x8*)(lds + bo + 16384 + boff);
    bR[1] = *(const bf16x8*)(lds + bo + 16384 + boff + 1024);
    stageA(nbuf, 1, nk0);
    PRIO1(); MFMA16(0); PRIO0();
    bR[0] = *(const bf16x8*)(lds + bo + 16384 + boff + 2048);
    bR[1] = *(const bf16x8*)(lds + bo + 16384 + boff + 3072);
    stageB(nbuf, 1, nk0);
    PRIO1(); MFMA16(2); PRIO0();
    VMW4();
    SBAR(); FEN();
  }
  {
    const int bo = 32768;
#pragma unroll
    for (int mi = 0; mi < 8; ++mi) aR[mi] = *(const bf16x8*)(lds + bo + aoff + mi * 1024);
    bR[0] = *(const bf16x8*)(lds + bo + boff);
    bR[1] = *(const bf16x8*)(lds + bo + boff + 1024);
    PRIO1(); MFMA16(0); PRIO0();
    bR[0] = *(const bf16x8*)(lds + bo + boff + 2048);
    bR[1] = *(const bf16x8*)(lds + bo + boff + 3072);
    PRIO1(); MFMA16(2); PRIO0();
    VMW0();
    SBAR(); FEN();
#pragma unroll
    for (int mi = 0; mi < 8; ++mi) aR[mi] = *(const bf16x8*)(lds + bo + 16384 + aoff + mi * 1024);
    bR[0] = *(const bf16x8*)(lds + bo + 16384 + boff);
    bR[1] = *(const bf16x8*)(lds + bo + 16384 + boff + 1024);
    PRIO1(); MFMA16(0); PRIO0();
    bR[0] = *(const bf16x8*)(lds + bo + 16384 + boff + 2048);
    bR[1] = *(const bf16x8*)(lds + bo + 16384 + boff + 3072);
    PRIO1(); MFMA16(2); PRIO0();
  }

  float* Cc = attn + ((size_t)h << 22);
  const int rbase = tm + (wr << 7) + ((lane >> 4) << 2);
  const int cbase = tn + (wc << 6) + f;
#pragma unroll
  for (int mi = 0; mi < 8; ++mi)
#pragma unroll
    for (int i = 0; i < 4; ++i) {
      float* rp = Cc + ((size_t)(rbase + mi * 16 + i) << 11) + cbase;
#pragma unroll
      for (int ni = 0; ni < 4; ++ni) rp[ni * 16] = acc[mi][ni][i];
    }
}

// ---------------- context GEMM (K-split) ----------------
__global__ __launch_bounds__(256) void k_ctx(
    const __hip_bfloat16* __restrict__ vfT, const __hip_bfloat16* __restrict__ kfT,
    float* __restrict__ ctxp) {
  __shared__ __align__(16) __bf16 As[4096], Bs[4096];
  const int z = blockIdx.z, h = z >> 2, kc = z & 3;
  const int tn = blockIdx.y << 7;
  f32x4 acc[4][4];
  ZERO_ACC(acc);
  gemm_core(vfT + ((size_t)h << 18) + (kc << 9), kfT + ((size_t)h << 21) + (kc << 9),
            2048, 2048, 512, 0, tn, As, Bs, acc);
  float* Cp = ctxp + ((size_t)(kc * 8 + h) << 17);
  const int t = threadIdx.x, w = t >> 6, lane = t & 63;
  const int m_off = (w >> 1) << 6, n_off = (w & 1) << 6;
#pragma unroll
  for (int mi = 0; mi < 4; ++mi)
#pragma unroll
    for (int i = 0; i < 4; ++i) {
      const int row = m_off + mi * 16 + ((lane >> 4) << 2) + i;
#pragma unroll
      for (int ni = 0; ni < 4; ++ni) {
        const int col = tn + n_off + ni * 16 + (lane & 15);
        Cp[((size_t)row << 10) + col] = acc[mi][ni][i];
      }
    }
}

__global__ void k_ctxred(const float* __restrict__ ctxp, __hip_bfloat16* __restrict__ ctxT) {
  const int i = (blockIdx.x * 256 + threadIdx.x) * 4;
  f32x4 a = *(const f32x4*)(ctxp + i);
  f32x4 b = *(const f32x4*)(ctxp + i + 1048576);
  f32x4 c = *(const f32x4*)(ctxp + i + 2097152);
  f32x4 d = *(const f32x4*)(ctxp + i + 3145728);
  bf16x4 o;
#pragma unroll
  for (int j = 0; j < 4; ++j) o[j] = (__bf16)(a[j] + b[j] + c[j] + d[j]);
  *(bf16x4*)((__bf16*)ctxT + i) = o;
}

// ---------------- out GEMM (64-row tiles) + D_inv + scatter ----------------
__global__ __launch_bounds__(256) void k_out64(
    const __hip_bfloat16* __restrict__ qf, const __hip_bfloat16* __restrict__ ctxT,
    const float* __restrict__ dpart, float* __restrict__ outp) {
  __shared__ __align__(16) __bf16 As[2048], Bs[4096];
  __shared__ float dinv_s[64];
  const int h = blockIdx.z;
  const int tm = blockIdx.x << 6;
  const int t = threadIdx.x, w = t >> 6, lane = t & 63;
  if (t < 64) {
    float s = 0.f;
#pragma unroll
    for (int r = 0; r < 8; ++r) s += dpart[(((r << 3) + h) << 11) + tm + t];
    dinv_s[t] = 1.0f / s;
  }
  const int m_off = (w >> 1) << 5, n_off = (w & 1) << 6;
  const int r0 = t >> 2, kk = (t & 3) << 3;
  char* Asb = (char*)As + ((t >> 6) << 10);
  char* Bsb = (char*)Bs + ((t >> 6) << 10);
  const int frow = lane & 15, koff = (lane >> 4) << 3;
  const __hip_bfloat16* A = qf + ((size_t)h << 21);
  const __hip_bfloat16* B = ctxT + ((size_t)h << 17);
  f32x4 acc[2][4];
#pragma unroll
  for (int a_ = 0; a_ < 2; ++a_)
#pragma unroll
    for (int b_ = 0; b_ < 4; ++b_) acc[a_][b_] = (f32x4){0.f, 0.f, 0.f, 0.f};
  for (int k0 = 0; k0 < 1024; k0 += 32) {
    const __hip_bfloat16* Agp = A + (size_t)(tm + r0) * 1024 + (k0 + kk);
    const __hip_bfloat16* Bgp = B + (size_t)r0 * 1024 + (k0 + kk);
    gload16(Agp, Asb);
    gload16(Bgp, Bsb);
    gload16(Bgp + (size_t)64 * 1024, Bsb + 4096);
    __syncthreads();
    bf16x8 af[2], bfr[4];
#pragma unroll
    for (int mi = 0; mi < 2; ++mi)
      af[mi] = *(const bf16x8*)(As + ((m_off + mi * 16 + frow) << 5) + koff);
#pragma unroll
    for (int ni = 0; ni < 4; ++ni)
      bfr[ni] = *(const bf16x8*)(Bs + ((n_off + ni * 16 + frow) << 5) + koff);
#pragma unroll
    for (int mi = 0; mi < 2; ++mi)
#pragma unroll
      for (int ni = 0; ni < 4; ++ni)
        acc[mi][ni] = __builtin_amdgcn_mfma_f32_16x16x32_bf16(af[mi], bfr[ni], acc[mi][ni], 0, 0, 0);
    __syncthreads();
  }
#pragma unroll
  for (int mi = 0; mi < 2; ++mi)
#pragma unroll
    for (int i = 0; i < 4; ++i) {
      const int rl = m_off + mi * 16 + ((lane >> 4) << 2) + i;
      const int row = tm + rl;
      const float dv = dinv_s[rl];
#pragma unroll
      for (int ni = 0; ni < 4; ++ni) {
        const int col = n_off + ni * 16 + frow;
        const int rb = col >> 4, tt = col & 15;
        outp[(((size_t)(rb << 11) + row) << 7) + (h << 4) + tt] = acc[mi][ni][i] * dv;
      }
    }
}

// ---------------- launch ----------------
extern "C" void kernel_launch(void* const* d_in, const int* in_sizes, int n_in,
                              void* d_out, int out_size, void* d_ws, size_t ws_size,
                              hipStream_t stream) {
  const float* x    = (const float*)d_in[0];
  const float* Wq   = (const float*)d_in[1];
  const float* bq   = (const float*)d_in[2];
  const float* Wk   = (const float*)d_in[3];
  const float* bk   = (const float*)d_in[4];
  const float* Wv   = (const float*)d_in[5];
  const float* bv   = (const float*)d_in[6];
  const float* proj = (const float*)d_in[7];
  if (ws_size < WS_NEED) return;

  char* ws = (char*)d_ws;
  __hip_bfloat16* xb   = (__hip_bfloat16*)(ws + OFF_XB);
  __hip_bfloat16* Wcat = (__hip_bfloat16*)(ws + OFF_WCAT);
  __hip_bfloat16* Mq   = (__hip_bfloat16*)(ws + OFF_MQ);
  __hip_bfloat16* Mk   = (__hip_bfloat16*)(ws + OFF_MK);
  float* bcat = (float*)(ws + OFF_BCAT);
  float* bqf  = (float*)(ws + OFF_BQF);
  float* bkf  = (float*)(ws + OFF_BKF);
  float* Y    = (float*)(ws + OFF_Y);
  __hip_bfloat16* qf  = (__hip_bfloat16*)(ws + OFF_QF);
  __hip_bfloat16* kf  = (__hip_bfloat16*)(ws + OFF_KF);
  __hip_bfloat16* kfT = (__hip_bfloat16*)(ws + OFF_KFT);
  __hip_bfloat16* vfT = (__hip_bfloat16*)(ws + OFF_VFT);
  float* kpart  = (float*)(ws + OFF_KPART);
  unsigned* kmaxI = (unsigned*)(ws + OFF_KMAX);
  float* kspart = (float*)(ws + OFF_KSPART);
  float* dpart  = (float*)(ws + OFF_DPART);
  float* ctxp   = (float*)(ws + OFF_CTXP);
  __hip_bfloat16* ctxT = (__hip_bfloat16*)(ws + OFF_CTXT);

  float* outp = (float*)d_out;
  float* attn = (float*)d_out + 2097152;

  static int attr_done = 0;
  if (!attr_done) {
    (void)hipFuncSetAttribute((const void*)k_attn8,
                              hipFuncAttributeMaxDynamicSharedMemorySize, 131072);
    attr_done = 1;
  }

  k_prep<<<dim3(2048), dim3(256), 0, stream>>>(x, Wq, bq, Wk, bk, Wv, bv, proj,
                                               xb, Wcat, bcat, Mq, Mk, bqf, bkf, kmaxI);
  k_proj<<<dim3(128, 3), dim3(256), 0, stream>>>(xb, Wcat, bcat, Y, vfT);
  {
    void* args[] = {(void*)&xb, (void*)&Mk, (void*)&bkf, (void*)&Y,
                    (void*)&kmaxI, (void*)&kf, (void*)&kfT, (void*)&kspart};
    hipError_t e = hipLaunchCooperativeKernel((void*)k_dashk_coop, dim3(128, 8),
                                              dim3(256), args, 0, stream);
    if (e != hipSuccess) {
      (void)hipGetLastError();  // clear
      k_dashk_max<<<dim3(128, 8), dim3(256), 0, stream>>>(xb, Mk, bkf, kpart);
      // reduce kpart -> inline in feat (reads all 16 per r)
      k_dashk_feat<<<dim3(128, 8), dim3(256), 0, stream>>>(xb, Mk, bkf, Y, kpart, kf, kfT, kspart);
    }
  }
  k_dashq<<<dim3(128, 8), dim3(256), 0, stream>>>(xb, Mq, bqf, Y, kspart, qf, dpart);
  k_attn8<<<dim3(512), dim3(512), 131072, stream>>>(qf, kf, attn);
  k_ctx<<<dim3(1, 8, 32), dim3(256), 0, stream>>>(vfT, kfT, ctxp);
  k_ctxred<<<dim3(1024), dim3(256), 0, stream>>>(ctxp, ctxT);
  k_out64<<<dim3(32, 1, 8), dim3(256), 0, stream>>>(qf, ctxT, dpart, outp);
}

// Round 11
// 183.568 us; speedup vs baseline: 1.6459x; 1.6459x over previous
//
#include <hip/hip_runtime.h>
#include <hip/hip_bf16.h>
#include <stdint.h>

typedef __bf16 bf16x8 __attribute__((ext_vector_type(8)));
typedef __bf16 bf16x4 __attribute__((ext_vector_type(4)));
typedef float  f32x4  __attribute__((ext_vector_type(4)));

#define RATIO 0.08838834764831845f
#define EPSV  1e-4f

#define GLOBAL_AS __attribute__((address_space(1)))
#define LDS_AS    __attribute__((address_space(3)))

static __device__ __forceinline__ void gload16(const void* g, void* l) {
  __builtin_amdgcn_global_load_lds((GLOBAL_AS const void*)g, (LDS_AS void*)l, 16, 0, 0);
}

// ---------------- workspace layout (bytes) ----------------
static constexpr size_t OFF_XB    = 0;                        // 16384*128*2
static constexpr size_t OFF_WCAT  = OFF_XB    + 4194304;
static constexpr size_t OFF_MQ    = OFF_WCAT  + 98304;
static constexpr size_t OFF_MK    = OFF_MQ    + 262144;
static constexpr size_t OFF_BCAT  = OFF_MK    + 262144;
static constexpr size_t OFF_BQF   = OFF_BCAT  + 2048;
static constexpr size_t OFF_BKF   = OFF_BQF   + 4096;
static constexpr size_t OFF_Y     = OFF_BKF   + 4096;         // 16384*384*4
static constexpr size_t OFF_QF    = OFF_Y     + 25165824;     // 8*2048*1024*2
static constexpr size_t OFF_KF    = OFF_QF    + 33554432;
static constexpr size_t OFF_KFT   = OFF_KF    + 33554432;
static constexpr size_t OFF_VFT   = OFF_KFT   + 33554432;     // 8*128*2048*2
static constexpr size_t OFF_KPART = OFF_VFT   + 4194304;      // 8*128*4
static constexpr size_t OFF_KMAX  = OFF_KPART + 4096;         // pad
static constexpr size_t OFF_KSPART= OFF_KMAX  + 1024;         // 16*8*1024*4
static constexpr size_t OFF_DPART = OFF_KSPART+ 524288;       // 8*8*2048*4
static constexpr size_t OFF_CTXP  = OFF_DPART + 524288;       // 4*8*128*1024*4
static constexpr size_t OFF_CTXT  = OFF_CTXP  + 16777216;     // 8*128*1024*2
static constexpr size_t WS_NEED   = OFF_CTXT  + 2097152;

// ---------------- 2-phase NT-GEMM core (K-loop; used by k_ctx/k_out64) ------
static __device__ __forceinline__ void gemm_core(
    const __hip_bfloat16* __restrict__ A, const __hip_bfloat16* __restrict__ B,
    int lda, int ldb, int K, int tm, int tn,
    __bf16* As, __bf16* Bs, f32x4 acc[4][4]) {
  const int t    = threadIdx.x;
  const int w    = t >> 6;
  const int lane = t & 63;
  const int m_off = (w >> 1) << 6;
  const int n_off = (w & 1) << 6;
  const int r0 = t >> 2;
  const int kk = (t & 3) << 3;
  char* Asb = (char*)As + (w << 10);
  char* Bsb = (char*)Bs + (w << 10);
  const int frow = lane & 15;
  const int koff = (lane >> 4) << 3;
  for (int k0 = 0; k0 < K; k0 += 32) {
    const __hip_bfloat16* Ag = A + (size_t)(tm + r0) * lda + (k0 + kk);
    const __hip_bfloat16* Bg = B + (size_t)(tn + r0) * ldb + (k0 + kk);
    gload16(Ag, Asb);
    gload16(Ag + (size_t)64 * lda, Asb + 4096);
    gload16(Bg, Bsb);
    gload16(Bg + (size_t)64 * ldb, Bsb + 4096);
    __syncthreads();
    bf16x8 af[4], bfr[4];
#pragma unroll
    for (int mi = 0; mi < 4; ++mi)
      af[mi] = *(const bf16x8*)(As + ((m_off + mi * 16 + frow) << 5) + koff);
#pragma unroll
    for (int ni = 0; ni < 4; ++ni)
      bfr[ni] = *(const bf16x8*)(Bs + ((n_off + ni * 16 + frow) << 5) + koff);
#pragma unroll
    for (int mi = 0; mi < 4; ++mi)
#pragma unroll
      for (int ni = 0; ni < 4; ++ni)
        acc[mi][ni] = __builtin_amdgcn_mfma_f32_16x16x32_bf16(af[mi], bfr[ni], acc[mi][ni], 0, 0, 0);
    __syncthreads();
  }
}

// ---------------- single-stage K=128 NT-GEMM core (XOR-granule swizzle) ------
// LDS: As/Bs each [128 rows][256B]; granule g (16B) at row*256+g*16 holds
// source elems ((g ^ (row&15))*8 ..+7).  Both-sides swizzle: inverse on the
// global source (linear gload_lds dest), forward on the ds_read address.
// Accumulation order identical to gemm_core (k0 = 0,32,64,96) -> bit-identical.
static __device__ __forceinline__ void gemm_core_k128(
    const __hip_bfloat16* __restrict__ A, const __hip_bfloat16* __restrict__ B,
    int lda, int ldb, int tm, int tn,
    __bf16* As, __bf16* Bs, f32x4 acc[4][4]) {
  const int t = threadIdx.x, w = t >> 6, lane = t & 63;
  const int m_off = (w >> 1) << 6, n_off = (w & 1) << 6;
  const int frow = lane & 15;
  const int g0 = lane >> 4;
  const int srow = (w << 5) + (lane >> 4);
  const int sg = lane & 15;
  char* Ab = (char*)As + (w << 13);
  char* Bb = (char*)Bs + (w << 13);
#pragma unroll
  for (int j = 0; j < 8; ++j) {
    const int row = srow + (j << 2);
    const int scol = (sg ^ (row & 15)) << 3;
    gload16(A + (size_t)(tm + row) * lda + scol, Ab + (j << 10));
    gload16(B + (size_t)(tn + row) * ldb + scol, Bb + (j << 10));
  }
  __syncthreads();
#pragma unroll
  for (int kk = 0; kk < 4; ++kk) {
    bf16x8 af[4], bfr[4];
#pragma unroll
    for (int mi = 0; mi < 4; ++mi) {
      const int row = m_off + mi * 16 + frow;
      const int gr = ((kk << 2) + g0) ^ (row & 15);
      af[mi] = *(const bf16x8*)((char*)As + row * 256 + gr * 16);
    }
#pragma unroll
    for (int ni = 0; ni < 4; ++ni) {
      const int row = n_off + ni * 16 + frow;
      const int gr = ((kk << 2) + g0) ^ (row & 15);
      bfr[ni] = *(const bf16x8*)((char*)Bs + row * 256 + gr * 16);
    }
#pragma unroll
    for (int mi = 0; mi < 4; ++mi)
#pragma unroll
      for (int ni = 0; ni < 4; ++ni)
        acc[mi][ni] = __builtin_amdgcn_mfma_f32_16x16x32_bf16(af[mi], bfr[ni], acc[mi][ni], 0, 0, 0);
  }
  __syncthreads();   // LDS reusable after
}

#define ZERO_ACC(acc) do {                                   \
  _Pragma("unroll") for (int a_ = 0; a_ < 4; ++a_)           \
  _Pragma("unroll") for (int b_ = 0; b_ < 4; ++b_)           \
    acc[a_][b_] = (f32x4){0.f, 0.f, 0.f, 0.f};               \
} while (0)

// ---------------- fused prep kernel ----------------
__global__ void k_prep(const float* __restrict__ x,
                       const float* __restrict__ Wq, const float* __restrict__ bq,
                       const float* __restrict__ Wk, const float* __restrict__ bk,
                       const float* __restrict__ Wv, const float* __restrict__ bv,
                       const float* __restrict__ proj,
                       __hip_bfloat16* __restrict__ xb,
                       __hip_bfloat16* __restrict__ Wcat, float* __restrict__ bcat,
                       __hip_bfloat16* __restrict__ Mq, __hip_bfloat16* __restrict__ Mk,
                       float* __restrict__ bqf, float* __restrict__ bkf) {
  const int b = blockIdx.x, t = threadIdx.x;
  { // convx
    int i = (b * 256 + t) * 4;
    f32x4 v = *(const f32x4*)(x + i);
#pragma unroll
    for (int j = 0; j < 4; ++j) xb[i + j] = __float2bfloat16(v[j]);
  }
  if (b < 1024) { // prepM
    int i = b * 256 + t;
    {
      int which = i >> 17;
      int rem = i & 131071;
      int hj = rem >> 7, e = rem & 127;
      int hh = hj >> 7, j = hj & 127;
      const float* W = which ? Wk : Wq;
      float s = 0.f;
#pragma unroll
      for (int u = 0; u < 16; ++u) s += proj[j * 16 + u] * W[(hh * 16 + u) * 128 + e];
      if (which) Mk[rem] = __float2bfloat16(0.5f * s);
      else       Mq[rem] = __float2bfloat16(0.5f * s);
    }
    if (i < 2048) {
      int which = i >> 10;
      int hj = i & 1023, hh = hj >> 7, j = hj & 127;
      const float* bb = which ? bk : bq;
      float s = 0.f;
#pragma unroll
      for (int u = 0; u < 16; ++u) s += proj[j * 16 + u] * bb[hh * 16 + u];
      if (which) bkf[hj] = 0.5f * s;
      else       bqf[hj] = 0.5f * s;
    }
  }
  if (b < 192) { // prepwb
    int i = b * 256 + t;
    int mat = i >> 14, rem = i & 16383;
    const float* W = (mat == 0) ? Wq : ((mat == 1) ? Wk : Wv);
    Wcat[i] = __float2bfloat16(W[rem]);
    if (i < 384) {
      int m2 = i >> 7;
      const float* bb = (m2 == 0) ? bq : ((m2 == 1) ? bk : bv);
      bcat[i] = bb[i & 127];
    }
  }
}

// ---------------- projection GEMM: Y = x*Wcat^T + bcat; V-part -> vfT --------
__global__ __launch_bounds__(256) void k_proj(
    const __hip_bfloat16* __restrict__ xb, const __hip_bfloat16* __restrict__ Wcat,
    const float* __restrict__ bcat, float* __restrict__ Y,
    __hip_bfloat16* __restrict__ vfT) {
  __shared__ __align__(16) char pool[65536];   // As(32K)+Bs(32K); vT reuse after
  __bf16* As = (__bf16*)pool;
  __bf16* Bs = (__bf16*)(pool + 32768);
  const int tm = blockIdx.x << 7, tn = blockIdx.y << 7;
  f32x4 acc[4][4];
  ZERO_ACC(acc);
  gemm_core_k128(xb, Wcat, 128, 128, tm, tn, As, Bs, acc);
  const int t = threadIdx.x, w = t >> 6, lane = t & 63;
  const int m_off = (w >> 1) << 6, n_off = (w & 1) << 6;
  const int frow = lane & 15;
  if (tn == 256) {
    __bf16* vT = (__bf16*)pool;   // reuse (core ends with barrier)
#pragma unroll
    for (int ni = 0; ni < 4; ++ni) {
      const int j = n_off + ni * 16 + frow;
      const float bias = bcat[256 + j];
#pragma unroll
      for (int mi = 0; mi < 4; ++mi)
#pragma unroll
        for (int i = 0; i < 4; ++i) {
          const int rl = m_off + mi * 16 + ((lane >> 4) << 2) + i;
          vT[j * 136 + rl] = (__bf16)(acc[mi][ni][i] + bias);
        }
    }
    __syncthreads();
    const int r = tm >> 11, c0 = tm & 2047;
    const int j2 = t >> 1, half = t & 1;
    const int hh = j2 >> 4, aa = j2 & 15;
    __bf16* dst = (__bf16*)vfT + (((size_t)(hh * 128 + r * 16 + aa)) << 11) + c0 + (half << 6);
    const __bf16* srcr = vT + j2 * 136 + (half << 6);
#pragma unroll
    for (int q8 = 0; q8 < 8; ++q8)
      *(bf16x8*)(dst + (q8 << 3)) = *(const bf16x8*)(srcr + (q8 << 3));
  } else {
#pragma unroll
    for (int ni = 0; ni < 4; ++ni) {
      const int col = tn + n_off + ni * 16 + frow;
      const float bias = bcat[col];
#pragma unroll
      for (int mi = 0; mi < 4; ++mi)
#pragma unroll
        for (int i = 0; i < 4; ++i) {
          const int row = tm + m_off + mi * 16 + ((lane >> 4) << 2) + i;
          Y[(size_t)row * 384 + col] = acc[mi][ni][i] + bias;
        }
    }
  }
}

// ---------------- k features: pass A (max) ----------------
__global__ __launch_bounds__(256) void k_dashk_max(
    const __hip_bfloat16* __restrict__ xb, const __hip_bfloat16* __restrict__ Mk,
    const float* __restrict__ bkf, float* __restrict__ kpart) {
  __shared__ __align__(16) char pool[65536];
  __shared__ float wmax[4];
  __bf16* As = (__bf16*)pool;
  __bf16* Bs = (__bf16*)(pool + 32768);
  const int h = blockIdx.y;
  const int tm = blockIdx.x << 7;
  f32x4 acc[4][4];
  ZERO_ACC(acc);
  gemm_core_k128(xb, Mk + h * 16384, 128, 128, tm, 0, As, Bs, acc);
  const int t = threadIdx.x, w = t >> 6, lane = t & 63;
  const int n_off = (w & 1) << 6;
  float mx = -1e30f;
#pragma unroll
  for (int ni = 0; ni < 4; ++ni) {
    const float bia = bkf[h * 128 + n_off + ni * 16 + (lane & 15)];
#pragma unroll
    for (int mi = 0; mi < 4; ++mi)
#pragma unroll
      for (int i = 0; i < 4; ++i) mx = fmaxf(mx, acc[mi][ni][i] + bia);
  }
#pragma unroll
  for (int off = 1; off < 64; off <<= 1) mx = fmaxf(mx, __shfl_xor(mx, off));
  if (lane == 0) wmax[w] = mx;
  __syncthreads();
  if (t == 0) kpart[h * 128 + blockIdx.x] = fmaxf(fmaxf(wmax[0], wmax[1]), fmaxf(wmax[2], wmax[3]));
}

// ---------------- k features: pass B (kf + kfT + ksum partials) ----------
__global__ __launch_bounds__(256) void k_dashk_feat(
    const __hip_bfloat16* __restrict__ xb, const __hip_bfloat16* __restrict__ Mk,
    const float* __restrict__ bkf, const float* __restrict__ Y,
    const float* __restrict__ kpart,
    __hip_bfloat16* __restrict__ kf, __hip_bfloat16* __restrict__ kfT,
    float* __restrict__ kspart) {
  __shared__ __align__(16) char pool[65536];   // As/Bs; kT[128*136]bf16 reuse
  __shared__ float diag_s[128];
  __shared__ float ksp_s[2][128];
  __bf16* As = (__bf16*)pool;
  __bf16* Bs = (__bf16*)(pool + 32768);
  __bf16* kT = (__bf16*)pool;
  const int h = blockIdx.y;
  const int tm = blockIdx.x << 7;
  const int t = threadIdx.x, w = t >> 6, lane = t & 63;
  if (t < 128) {
    const float* yp = Y + (size_t)(tm + t) * 384 + 128 + h * 16;
    float s = 0.f;
#pragma unroll
    for (int u = 0; u < 16; ++u) s += yp[u] * yp[u];
    diag_s[t] = 0.125f * s;
  }
  f32x4 acc[4][4];
  ZERO_ACC(acc);
  gemm_core_k128(xb, Mk + h * 16384, 128, 128, tm, 0, As, Bs, acc);
  const int m_off = (w >> 1) << 6, n_off = (w & 1) << 6;
  const int frow = lane & 15;
  const int r = tm >> 11;
  const int c0 = tm & 2047;
  const int cb = blockIdx.x & 15;
  float m = -1e30f;
  {
    const float* kp = kpart + h * 128 + r * 16;
#pragma unroll
    for (int i = 0; i < 16; ++i) m = fmaxf(m, kp[i]);
  }
  float bia[4];
#pragma unroll
  for (int ni = 0; ni < 4; ++ni) bia[ni] = bkf[h * 128 + n_off + ni * 16 + frow];
  float ksp[4] = {0.f, 0.f, 0.f, 0.f};
#pragma unroll
  for (int mi = 0; mi < 4; ++mi) {
#pragma unroll
    for (int i = 0; i < 4; ++i) {
      const int rl = m_off + mi * 16 + ((lane >> 4) << 2) + i;
      const int c = c0 + rl;
      const float dm = diag_s[rl] + m;
#pragma unroll
      for (int ni = 0; ni < 4; ++ni) {
        const int j = n_off + ni * 16 + frow;
        const float f = RATIO * (__expf(acc[mi][ni][i] + bia[ni] - dm) + EPSV);
        const __hip_bfloat16 hb = __float2bfloat16(f);
        kf[((size_t)((h << 11) + c) << 10) + (r << 7) + j] = hb;
        kT[j * 136 + rl] = (__bf16)f;
        ksp[ni] += __bfloat162float(hb);
      }
    }
  }
#pragma unroll
  for (int ni = 0; ni < 4; ++ni) {
    ksp[ni] += __shfl_xor(ksp[ni], 16);
    ksp[ni] += __shfl_xor(ksp[ni], 32);
  }
  if ((lane >> 4) == 0) {
#pragma unroll
    for (int ni = 0; ni < 4; ++ni)
      ksp_s[w >> 1][n_off + ni * 16 + frow] = ksp[ni];
  }
  __syncthreads();
  if (t < 128)
    kspart[(((cb << 3) + h) << 10) + r * 128 + t] = ksp_s[0][t] + ksp_s[1][t];
  const int j2 = t >> 1, half = t & 1;
  __bf16* dst = (__bf16*)kfT + (((size_t)(h << 10) + (r << 7) + j2) << 11) + c0 + (half << 6);
  const __bf16* srcr = kT + j2 * 136 + (half << 6);
#pragma unroll
  for (int q8 = 0; q8 < 8; ++q8)
    *(bf16x8*)(dst + (q8 << 3)) = *(const bf16x8*)(srcr + (q8 << 3));
}

// ---------------- q features (+ fused D_inv partial dot) ----------
__global__ __launch_bounds__(256) void k_dashq(
    const __hip_bfloat16* __restrict__ xb, const __hip_bfloat16* __restrict__ Mq,
    const float* __restrict__ bqf, const float* __restrict__ Y,
    const float* __restrict__ kspart,
    __hip_bfloat16* __restrict__ qf, float* __restrict__ dpart) {
  __shared__ __align__(16) char pool[65536];
  __shared__ float diag_s[128];
  __shared__ float rmax_s[2][128];
  __shared__ float ksum_s[128];
  __shared__ float dred_s[2][128];
  __bf16* As = (__bf16*)pool;
  __bf16* Bs = (__bf16*)(pool + 32768);
  const int h = blockIdx.y;
  const int tm = blockIdx.x << 7;
  const int r = tm >> 11, c0 = tm & 2047;
  f32x4 acc[4][4];
  ZERO_ACC(acc);
  const int t = threadIdx.x, w = t >> 6, lane = t & 63;
  if (t < 128) {
    const float* yp = Y + (size_t)(tm + t) * 384 + h * 16;
    float s = 0.f;
#pragma unroll
    for (int u = 0; u < 16; ++u) s += yp[u] * yp[u];
    diag_s[t] = 0.125f * s;
    float ks = 0.f;
#pragma unroll
    for (int cb = 0; cb < 16; ++cb) ks += kspart[(((cb << 3) + h) << 10) + r * 128 + t];
    ksum_s[t] = ks;
  }
  gemm_core_k128(xb, Mq + h * 16384, 128, 128, tm, 0, As, Bs, acc);
  const int m_off = (w >> 1) << 6, n_off = (w & 1) << 6;
  const int frow = lane & 15;
  float bia[4];
#pragma unroll
  for (int ni = 0; ni < 4; ++ni) bia[ni] = bqf[h * 128 + n_off + ni * 16 + frow];
  float rmx[4][4];
#pragma unroll
  for (int mi = 0; mi < 4; ++mi)
#pragma unroll
    for (int i = 0; i < 4; ++i) {
      float m0 = acc[mi][0][i] + bia[0];
      m0 = fmaxf(m0, acc[mi][1][i] + bia[1]);
      m0 = fmaxf(m0, acc[mi][2][i] + bia[2]);
      m0 = fmaxf(m0, acc[mi][3][i] + bia[3]);
      rmx[mi][i] = m0;
    }
#pragma unroll
  for (int off = 1; off < 16; off <<= 1)
#pragma unroll
    for (int mi = 0; mi < 4; ++mi)
#pragma unroll
      for (int i = 0; i < 4; ++i)
        rmx[mi][i] = fmaxf(rmx[mi][i], __shfl_xor(rmx[mi][i], off));
  if (frow == 0) {
#pragma unroll
    for (int mi = 0; mi < 4; ++mi)
#pragma unroll
      for (int i = 0; i < 4; ++i)
        rmax_s[w & 1][m_off + mi * 16 + ((lane >> 4) << 2) + i] = rmx[mi][i];
  }
  __syncthreads();
  float p[4][4];
#pragma unroll
  for (int mi = 0; mi < 4; ++mi)
#pragma unroll
    for (int i = 0; i < 4; ++i) p[mi][i] = 0.f;
#pragma unroll
  for (int mi = 0; mi < 4; ++mi) {
#pragma unroll
    for (int i = 0; i < 4; ++i) {
      const int rl = m_off + mi * 16 + ((lane >> 4) << 2) + i;
      const float md = diag_s[rl] + fmaxf(rmax_s[0][rl], rmax_s[1][rl]);
#pragma unroll
      for (int ni = 0; ni < 4; ++ni) {
        const int j = n_off + ni * 16 + frow;
        const float f = RATIO * (__expf(acc[mi][ni][i] + bia[ni] - md) + EPSV);
        const __hip_bfloat16 hb = __float2bfloat16(f);
        qf[((size_t)((h << 11) + c0 + rl) << 10) + (r << 7) + j] = hb;
        p[mi][i] += __bfloat162float(hb) * ksum_s[j];
      }
    }
  }
#pragma unroll
  for (int off = 1; off < 16; off <<= 1)
#pragma unroll
    for (int mi = 0; mi < 4; ++mi)
#pragma unroll
      for (int i = 0; i < 4; ++i)
        p[mi][i] += __shfl_xor(p[mi][i], off);
  if (frow == 0) {
#pragma unroll
    for (int mi = 0; mi < 4; ++mi)
#pragma unroll
      for (int i = 0; i < 4; ++i)
        dred_s[w & 1][m_off + mi * 16 + ((lane >> 4) << 2) + i] = p[mi][i];
  }
  __syncthreads();
  if (t < 128)
    dpart[(((r << 3) + h) << 11) + c0 + t] = dred_s[0][t] + dred_s[1][t];
}

// ---------------- attn GEMM: 256x256, BK=64, 4-phase (r9-exact) --------------
#define SBAR() __builtin_amdgcn_s_barrier()
#define FEN()  do { asm volatile("" ::: "memory"); __builtin_amdgcn_sched_barrier(0); } while (0)
#define PRIO1() __builtin_amdgcn_s_setprio(1)
#define PRIO0() __builtin_amdgcn_s_setprio(0)
#define VMW4() do { asm volatile("s_waitcnt vmcnt(4)" ::: "memory"); } while (0)
#define VMW0() do { asm volatile("s_waitcnt vmcnt(0)" ::: "memory"); } while (0)

#define MFMA16(nlo) do {                                                      \
  _Pragma("unroll") for (int mi_ = 0; mi_ < 8; ++mi_)                         \
  _Pragma("unroll") for (int nj_ = 0; nj_ < 2; ++nj_)                         \
    acc[mi_][(nlo) + nj_] = __builtin_amdgcn_mfma_f32_16x16x32_bf16(          \
        aR[mi_], bR[nj_], acc[mi_][(nlo) + nj_], 0, 0, 0);                    \
} while (0)

__global__ __launch_bounds__(512, 2) void k_attn8(
    const __hip_bfloat16* __restrict__ qf, const __hip_bfloat16* __restrict__ kf,
    float* __restrict__ attn) {
  extern __shared__ __align__(128) char lds[];
  const int lid = blockIdx.x;
  const int swz = ((lid & 7) << 6) + (lid >> 3);
  const int h  = swz >> 6;
  const int tm = ((swz >> 3) & 7) << 8;
  const int tn = (swz & 7) << 8;
  const __hip_bfloat16* Ag = qf + ((size_t)h << 21);
  const __hip_bfloat16* Bg = kf + ((size_t)h << 21);

  const int t = threadIdx.x, wid = t >> 6, lane = t & 63;
  const int f = lane & 15;
  const int wr = wid >> 2, wc = wid & 3;
  const int swzg = (((lane >> 4) ^ ((f >> 1) & 3)) << 4);
  const int aoff = ((wr << 7) + f) * 64 + swzg;
  const int boff = 65536 + ((wc << 6) + f) * 64 + swzg;
  const int srow = t >> 2;
  const int scol = (((t & 3) ^ ((t >> 3) & 3)) << 3);
  const int sdst = wid << 10;

  f32x4 acc[8][4] = {};
  bf16x8 aR[8], bR[2];

  auto stageA = [&](int buf, int kh, int k0) {
    char* d = lds + buf * 32768 + kh * 16384 + sdst;
    const __hip_bfloat16* g = Ag + (size_t)(tm + srow) * 1024 + k0 + (kh << 5) + scol;
    gload16(g, d);
    gload16(g + 128 * 1024, d + 8192);
  };
  auto stageB = [&](int buf, int kh, int k0) {
    char* d = lds + 65536 + buf * 32768 + kh * 16384 + sdst;
    const __hip_bfloat16* g = Bg + (size_t)(tn + srow) * 1024 + k0 + (kh << 5) + scol;
    gload16(g, d);
    gload16(g + 128 * 1024, d + 8192);
  };

  stageA(0, 0, 0); stageB(0, 0, 0); stageA(0, 1, 0); stageB(0, 1, 0);
  VMW4();
  SBAR(); FEN();

  for (int kt = 0; kt < 15; ++kt) {
    const int buf = kt & 1, nbuf = buf ^ 1;
    const int bo = buf * 32768;
    const int nk0 = (kt + 1) << 6;
#pragma unroll
    for (int mi = 0; mi < 8; ++mi) aR[mi] = *(const bf16x8*)(lds + bo + aoff + mi * 1024);
    bR[0] = *(const bf16x8*)(lds + bo + boff);
    bR[1] = *(const bf16x8*)(lds + bo + boff + 1024);
    stageA(nbuf, 0, nk0);
    PRIO1(); MFMA16(0); PRIO0();
    bR[0] = *(const bf16x8*)(lds + bo + boff + 2048);
    bR[1] = *(const bf16x8*)(lds + bo + boff + 3072);
    stageB(nbuf, 0, nk0);
    PRIO1(); MFMA16(2); PRIO0();
    VMW4();
    SBAR(); FEN();
#pragma unroll
    for (int mi = 0; mi < 8; ++mi) aR[mi] = *(const bf16x8*)(lds + bo + 16384 + aoff + mi * 1024);
    bR[0] = *(const bf16x8*)(lds + bo + 16384 + boff);
    bR[1] = *(const bf16x8*)(lds + bo + 16384 + boff + 1024);
    stageA(nbuf, 1, nk0);
    PRIO1(); MFMA16(0); PRIO0();
    bR[0] = *(const bf16x8*)(lds + bo + 16384 + boff + 2048);
    bR[1] = *(const bf16x8*)(lds + bo + 16384 + boff + 3072);
    stageB(nbuf, 1, nk0);
    PRIO1(); MFMA16(2); PRIO0();
    VMW4();
    SBAR(); FEN();
  }
  {
    const int bo = 32768;
#pragma unroll
    for (int mi = 0; mi < 8; ++mi) aR[mi] = *(const bf16x8*)(lds + bo + aoff + mi * 1024);
    bR[0] = *(const bf16x8*)(lds + bo + boff);
    bR[1] = *(const bf16x8*)(lds + bo + boff + 1024);
    PRIO1(); MFMA16(0); PRIO0();
    bR[0] = *(const bf16x8*)(lds + bo + boff + 2048);
    bR[1] = *(const bf16x8*)(lds + bo + boff + 3072);
    PRIO1(); MFMA16(2); PRIO0();
    VMW0();
    SBAR(); FEN();
#pragma unroll
    for (int mi = 0; mi < 8; ++mi) aR[mi] = *(const bf16x8*)(lds + bo + 16384 + aoff + mi * 1024);
    bR[0] = *(const bf16x8*)(lds + bo + 16384 + boff);
    bR[1] = *(const bf16x8*)(lds + bo + 16384 + boff + 1024);
    PRIO1(); MFMA16(0); PRIO0();
    bR[0] = *(const bf16x8*)(lds + bo + 16384 + boff + 2048);
    bR[1] = *(const bf16x8*)(lds + bo + 16384 + boff + 3072);
    PRIO1(); MFMA16(2); PRIO0();
  }

  float* Cc = attn + ((size_t)h << 22);
  const int rbase = tm + (wr << 7) + ((lane >> 4) << 2);
  const int cbase = tn + (wc << 6) + f;
#pragma unroll
  for (int mi = 0; mi < 8; ++mi)
#pragma unroll
    for (int i = 0; i < 4; ++i) {
      float* rp = Cc + ((size_t)(rbase + mi * 16 + i) << 11) + cbase;
#pragma unroll
      for (int ni = 0; ni < 4; ++ni) rp[ni * 16] = acc[mi][ni][i];
    }
}

// ---------------- context GEMM (K-split) ----------------
__global__ __launch_bounds__(256) void k_ctx(
    const __hip_bfloat16* __restrict__ vfT, const __hip_bfloat16* __restrict__ kfT,
    float* __restrict__ ctxp) {
  __shared__ __align__(16) __bf16 As[4096], Bs[4096];
  const int z = blockIdx.z, h = z >> 2, kc = z & 3;
  const int tn = blockIdx.y << 7;
  f32x4 acc[4][4];
  ZERO_ACC(acc);
  gemm_core(vfT + ((size_t)h << 18) + (kc << 9), kfT + ((size_t)h << 21) + (kc << 9),
            2048, 2048, 512, 0, tn, As, Bs, acc);
  float* Cp = ctxp + ((size_t)(kc * 8 + h) << 17);
  const int t = threadIdx.x, w = t >> 6, lane = t & 63;
  const int m_off = (w >> 1) << 6, n_off = (w & 1) << 6;
#pragma unroll
  for (int mi = 0; mi < 4; ++mi)
#pragma unroll
    for (int i = 0; i < 4; ++i) {
      const int row = m_off + mi * 16 + ((lane >> 4) << 2) + i;
#pragma unroll
      for (int ni = 0; ni < 4; ++ni) {
        const int col = tn + n_off + ni * 16 + (lane & 15);
        Cp[((size_t)row << 10) + col] = acc[mi][ni][i];
      }
    }
}

__global__ void k_ctxred(const float* __restrict__ ctxp, __hip_bfloat16* __restrict__ ctxT) {
  const int i = (blockIdx.x * 256 + threadIdx.x) * 4;
  f32x4 a = *(const f32x4*)(ctxp + i);
  f32x4 b = *(const f32x4*)(ctxp + i + 1048576);
  f32x4 c = *(const f32x4*)(ctxp + i + 2097152);
  f32x4 d = *(const f32x4*)(ctxp + i + 3145728);
  bf16x4 o;
#pragma unroll
  for (int j = 0; j < 4; ++j) o[j] = (__bf16)(a[j] + b[j] + c[j] + d[j]);
  *(bf16x4*)((__bf16*)ctxT + i) = o;
}

// ---------------- out GEMM (64-row tiles) + D_inv + scatter ----------------
__global__ __launch_bounds__(256) void k_out64(
    const __hip_bfloat16* __restrict__ qf, const __hip_bfloat16* __restrict__ ctxT,
    const float* __restrict__ dpart, float* __restrict__ outp) {
  __shared__ __align__(16) __bf16 As[2048], Bs[4096];
  __shared__ float dinv_s[64];
  const int h = blockIdx.z;
  const int tm = blockIdx.x << 6;
  const int t = threadIdx.x, w = t >> 6, lane = t & 63;
  if (t < 64) {
    float s = 0.f;
#pragma unroll
    for (int r = 0; r < 8; ++r) s += dpart[(((r << 3) + h) << 11) + tm + t];
    dinv_s[t] = 1.0f / s;
  }
  const int m_off = (w >> 1) << 5, n_off = (w & 1) << 6;
  const int r0 = t >> 2, kk = (t & 3) << 3;
  char* Asb = (char*)As + ((t >> 6) << 10);
  char* Bsb = (char*)Bs + ((t >> 6) << 10);
  const int frow = lane & 15, koff = (lane >> 4) << 3;
  const __hip_bfloat16* A = qf + ((size_t)h << 21);
  const __hip_bfloat16* B = ctxT + ((size_t)h << 17);
  f32x4 acc[2][4];
#pragma unroll
  for (int a_ = 0; a_ < 2; ++a_)
#pragma unroll
    for (int b_ = 0; b_ < 4; ++b_) acc[a_][b_] = (f32x4){0.f, 0.f, 0.f, 0.f};
  for (int k0 = 0; k0 < 1024; k0 += 32) {
    const __hip_bfloat16* Agp = A + (size_t)(tm + r0) * 1024 + (k0 + kk);
    const __hip_bfloat16* Bgp = B + (size_t)r0 * 1024 + (k0 + kk);
    gload16(Agp, Asb);
    gload16(Bgp, Bsb);
    gload16(Bgp + (size_t)64 * 1024, Bsb + 4096);
    __syncthreads();
    bf16x8 af[2], bfr[4];
#pragma unroll
    for (int mi = 0; mi < 2; ++mi)
      af[mi] = *(const bf16x8*)(As + ((m_off + mi * 16 + frow) << 5) + koff);
#pragma unroll
    for (int ni = 0; ni < 4; ++ni)
      bfr[ni] = *(const bf16x8*)(Bs + ((n_off + ni * 16 + frow) << 5) + koff);
#pragma unroll
    for (int mi = 0; mi < 2; ++mi)
#pragma unroll
      for (int ni = 0; ni < 4; ++ni)
        acc[mi][ni] = __builtin_amdgcn_mfma_f32_16x16x32_bf16(af[mi], bfr[ni], acc[mi][ni], 0, 0, 0);
    __syncthreads();
  }
#pragma unroll
  for (int mi = 0; mi < 2; ++mi)
#pragma unroll
    for (int i = 0; i < 4; ++i) {
      const int rl = m_off + mi * 16 + ((lane >> 4) << 2) + i;
      const int row = tm + rl;
      const float dv = dinv_s[rl];
#pragma unroll
      for (int ni = 0; ni < 4; ++ni) {
        const int col = n_off + ni * 16 + frow;
        const int rb = col >> 4, tt = col & 15;
        outp[(((size_t)(rb << 11) + row) << 7) + (h << 4) + tt] = acc[mi][ni][i] * dv;
      }
    }
}

// ---------------- launch ----------------
extern "C" void kernel_launch(void* const* d_in, const int* in_sizes, int n_in,
                              void* d_out, int out_size, void* d_ws, size_t ws_size,
                              hipStream_t stream) {
  const float* x    = (const float*)d_in[0];
  const float* Wq   = (const float*)d_in[1];
  const float* bq   = (const float*)d_in[2];
  const float* Wk   = (const float*)d_in[3];
  const float* bk   = (const float*)d_in[4];
  const float* Wv   = (const float*)d_in[5];
  const float* bv   = (const float*)d_in[6];
  const float* proj = (const float*)d_in[7];
  if (ws_size < WS_NEED) return;

  char* ws = (char*)d_ws;
  __hip_bfloat16* xb   = (__hip_bfloat16*)(ws + OFF_XB);
  __hip_bfloat16* Wcat = (__hip_bfloat16*)(ws + OFF_WCAT);
  __hip_bfloat16* Mq   = (__hip_bfloat16*)(ws + OFF_MQ);
  __hip_bfloat16* Mk   = (__hip_bfloat16*)(ws + OFF_MK);
  float* bcat = (float*)(ws + OFF_BCAT);
  float* bqf  = (float*)(ws + OFF_BQF);
  float* bkf  = (float*)(ws + OFF_BKF);
  float* Y    = (float*)(ws + OFF_Y);
  __hip_bfloat16* qf  = (__hip_bfloat16*)(ws + OFF_QF);
  __hip_bfloat16* kf  = (__hip_bfloat16*)(ws + OFF_KF);
  __hip_bfloat16* kfT = (__hip_bfloat16*)(ws + OFF_KFT);
  __hip_bfloat16* vfT = (__hip_bfloat16*)(ws + OFF_VFT);
  float* kpart  = (float*)(ws + OFF_KPART);
  float* kspart = (float*)(ws + OFF_KSPART);
  float* dpart  = (float*)(ws + OFF_DPART);
  float* ctxp   = (float*)(ws + OFF_CTXP);
  __hip_bfloat16* ctxT = (__hip_bfloat16*)(ws + OFF_CTXT);

  float* outp = (float*)d_out;
  float* attn = (float*)d_out + 2097152;

  static int attr_done = 0;
  if (!attr_done) {
    (void)hipFuncSetAttribute((const void*)k_attn8,
                              hipFuncAttributeMaxDynamicSharedMemorySize, 131072);
    attr_done = 1;
  }

  k_prep<<<dim3(2048), dim3(256), 0, stream>>>(x, Wq, bq, Wk, bk, Wv, bv, proj,
                                               xb, Wcat, bcat, Mq, Mk, bqf, bkf);
  k_proj<<<dim3(128, 3), dim3(256), 0, stream>>>(xb, Wcat, bcat, Y, vfT);
  k_dashk_max<<<dim3(128, 8), dim3(256), 0, stream>>>(xb, Mk, bkf, kpart);
  k_dashk_feat<<<dim3(128, 8), dim3(256), 0, stream>>>(xb, Mk, bkf, Y, kpart, kf, kfT, kspart);
  k_dashq<<<dim3(128, 8), dim3(256), 0, stream>>>(xb, Mq, bqf, Y, kspart, qf, dpart);
  k_attn8<<<dim3(512), dim3(512), 131072, stream>>>(qf, kf, attn);
  k_ctx<<<dim3(1, 8, 32), dim3(256), 0, stream>>>(vfT, kfT, ctxp);
  k_ctxred<<<dim3(1024), dim3(256), 0, stream>>>(ctxp, ctxT);
  k_out64<<<dim3(32, 1, 8), dim3(256), 0, stream>>>(qf, ctxT, dpart, outp);
}